// Round 4
// baseline (1540.994 us; speedup 1.0000x reference)
//
// EpisodicMemory: fp32 inputs/output.
//   prep_w    : one-shot fp32->bf16 conversion of fc1_w, W_ih, W_hh into ws.
//   g_kernel  : per-b block, feat@fc1w^T via 16x16x32 bf16 MFMA (unchanged).
//   scan_all  : R8 — attack the LDS pipeline (R7 counters: MfmaUtil 10%, step
//               dominated by 960 ds_read_b128/CU/step, 4x B-frag duplication,
//               16 syncs/step).
//               (1) Fat wave tiles: wave = 32 rows x 3 (gate,j) col-tiles
//                   -> B-dup 4x->2x, LDS reads 30->18/wave/kc.
//               (2) Wih B-frags loaded DIRECT from L2 as per-lane bf16x8 (same
//                   address the staging copy used -> byte-identical fragment);
//                   Wih staging removed. Whh stays LDS-resident (97.5 KB).
//               (3) Double-buffered As (c|h_hi|h_lo, 27 KB x2), ONE sync per kc:
//                   MFMA on buf[cur] overlaps staging writes into buf[cur^1].
//               (4) Gate partials land on different waves -> epilogue exchanges
//                   via 36 KB f32 LDS scratch ALIASING the As buffers (dead then).
//               Same accumulation order per accumulator -> bit-identical numerics.
//               Barrier: R7's fence-free per-b-tile progress slots (proven):
//               vmcnt(0) by ALL waves -> syncthreads -> t0 flags -> wave0 polls.
//               h packed (hi<<16|lo) device-scope sc0sc1, double-buffered.
#include <hip/hip_runtime.h>
#include <hip/hip_bf16.h>

#define H_ 512
#define SH_ 120
#define B_ 1024
#define S_ 64

typedef __bf16 bf16x8 __attribute__((ext_vector_type(8)));
typedef float floatx4 __attribute__((ext_vector_type(4)));

__device__ __forceinline__ float bf2f(ushort u) {
    union { unsigned int i; float f; } v; v.i = ((unsigned int)u) << 16; return v.f;
}
__device__ __forceinline__ ushort f2bf(float f) {
    union { float f; unsigned int i; } v; v.f = f;
    unsigned int x = v.i;
    unsigned int r = (x + 0x7fffu + ((x >> 16) & 1u)) >> 16;  // RNE
    return (ushort)r;
}

// Per-(group, member) progress slots. Group = b-tile (16 blocks), member = j-tile.
// Single writer per slot, monotone, never reset -> replay/graph-safe.
__device__ __attribute__((aligned(64))) unsigned g_prog[256];

// ---------------------------------------------------------------------------
// prep_w: one-shot fp32 -> bf16 of the three weight matrices.
// ---------------------------------------------------------------------------
__global__ __launch_bounds__(256) void prep_w(
    const float* __restrict__ fc1w, ushort* __restrict__ fc1wb,
    const float* __restrict__ Wih,  ushort* __restrict__ Wihb,
    const float* __restrict__ Whh,  ushort* __restrict__ Whhb)
{
    const int stride = gridDim.x * blockDim.x;
    const int tid = blockIdx.x * blockDim.x + threadIdx.x;
    for (int i = tid; i < 61440; i += stride) {            // 120*2048/4
        const float4 v = ((const float4*)fc1w)[i];
        ushort4 o; o.x = f2bf(v.x); o.y = f2bf(v.y); o.z = f2bf(v.z); o.w = f2bf(v.w);
        ((ushort4*)fc1wb)[i] = o;
    }
    for (int i = tid; i < 196608; i += stride) {           // 1536*512/4
        const float4 v = ((const float4*)Wih)[i];
        ushort4 o; o.x = f2bf(v.x); o.y = f2bf(v.y); o.z = f2bf(v.z); o.w = f2bf(v.w);
        ((ushort4*)Wihb)[i] = o;
    }
    for (int i = tid; i < 196608; i += stride) {
        const float4 v = ((const float4*)Whh)[i];
        ushort4 o; o.x = f2bf(v.x); o.y = f2bf(v.y); o.z = f2bf(v.z); o.w = f2bf(v.w);
        ((ushort4*)Whhb)[i] = o;
    }
}

// ---------------------------------------------------------------------------
// G kernel: one block per b. Computes G[b, s] for s=0..63. (unchanged)
// ---------------------------------------------------------------------------
__global__ __launch_bounds__(256) void g_kernel(
    const float* __restrict__ C, const float* __restrict__ Q,
    const float* __restrict__ M, const ushort* __restrict__ fc1wb,
    const float* __restrict__ fc1b, const float* __restrict__ fc2w,
    const float* __restrict__ fc2b, float* __restrict__ G)
{
    __shared__ float qrow[H_];
    __shared__ float mrow[H_];
    __shared__ __align__(16) ushort featT[64 * 72];   // 64 s-rows x 64 k (stride 72)
    __shared__ __align__(16) ushort wT[128 * 72];     // 128 n-rows x 64 k (rows>=120 zero)
    __shared__ float h1s[64 * 132];                   // 64 x 128 fp32 (stride 132)

    const int b = blockIdx.x;
    const int t = threadIdx.x;
    for (int i = t; i < H_; i += 256) { qrow[i] = Q[(size_t)b * H_ + i]; mrow[i] = M[(size_t)b * H_ + i]; }

    const int wrow = t >> 1;
    const int wc0  = (t & 1) * 32;
    if (wrow >= SH_) {              // zero-fill dead wT rows once
        uint4* dst = (uint4*)&wT[wrow * 72 + wc0];
        const uint4 z = {0u, 0u, 0u, 0u};
        dst[0] = z; dst[1] = z; dst[2] = z; dst[3] = z;
    }
    __syncthreads();

    const int lane = t & 63;
    const int wv   = t >> 6;
    const int quad = lane >> 4;
    const int l15  = lane & 15;
    const int arow = wv * 16 + l15;
    const int s    = t >> 2;
    const int c0   = (t & 3) * 16;

    floatx4 acc[8];
#pragma unroll
    for (int i = 0; i < 8; ++i) acc[i] = (floatx4){0.f, 0.f, 0.f, 0.f};

    for (int hc = 0; hc < H_; hc += 64) {
        float cr[16];
        {
            const float4* csrc = (const float4*)(C + ((size_t)b * S_ + s) * H_ + hc + c0);
            *(float4*)&cr[0]  = csrc[0];
            *(float4*)&cr[4]  = csrc[1];
            *(float4*)&cr[8]  = csrc[2];
            *(float4*)&cr[12] = csrc[3];
        }
#pragma unroll
        for (int seg = 0; seg < 4; ++seg) {
#pragma unroll
            for (int u = 0; u < 16; ++u) {
                const int kk = c0 + u;
                const float c = cr[u];
                const float o = (seg == 0 || seg == 2) ? qrow[hc + kk] : mrow[hc + kk];
                const float v = (seg < 2) ? c * o : fabsf(c - o);
                featT[s * 72 + kk] = f2bf(v);
            }
            if (wrow < SH_) {
                const uint4* src = (const uint4*)(fc1wb + (size_t)wrow * (4 * H_) + seg * H_ + hc + wc0);
                uint4* dst = (uint4*)&wT[wrow * 72 + wc0];
                dst[0] = src[0]; dst[1] = src[1]; dst[2] = src[2]; dst[3] = src[3];
            }
            __syncthreads();
#pragma unroll
            for (int ks = 0; ks < 64; ks += 32) {
                const int ao = ks + quad * 8;
                const bf16x8 af = *(const bf16x8*)&featT[arow * 72 + ao];
#pragma unroll
                for (int nt = 0; nt < 8; ++nt) {
                    const bf16x8 bfr = *(const bf16x8*)&wT[(nt * 16 + l15) * 72 + ao];
                    acc[nt] = __builtin_amdgcn_mfma_f32_16x16x32_bf16(af, bfr, acc[nt], 0, 0, 0);
                }
            }
            __syncthreads();
        }
    }

#pragma unroll
    for (int nt = 0; nt < 8; ++nt) {
        const int col = nt * 16 + l15;
        const float bias = (col < SH_) ? fc1b[col] : 0.f;
#pragma unroll
        for (int r = 0; r < 4; ++r) {
            const int row = wv * 16 + quad * 4 + r;
            h1s[row * 132 + col] = (col < SH_) ? tanhf(acc[nt][r] + bias) : 0.f;
        }
    }
    __syncthreads();
    {
        const int part = t & 3;
        float sum = 0.f;
        for (int k = part; k < SH_; k += 4) sum += h1s[s * 132 + k] * fc2w[k];
        sum += __shfl_xor(sum, 1);
        sum += __shfl_xor(sum, 2);
        if (part == 0) {
            const float logit = sum + fc2b[0];
            G[(size_t)b * S_ + s] = 1.f / (1.f + expf(-logit));
        }
    }
}

// ---------------------------------------------------------------------------
// scan_all: persistent scan. 256 blocks x 256 threads, 1 block/CU (151.5 KB LDS).
// Block = (j-tile 32 cols) x (b-tile 64 batches). Wave = 32 rows x 3 col-tiles.
// Col-tiles ctg 0..5 = (gate, j-half): 0:r/j0 1:r/j1 2:z/j0 3:z/j1 4:n/j0 5:n/j1.
// ---------------------------------------------------------------------------
__global__ __launch_bounds__(256) void scan_all(
    const float* __restrict__ C, const ushort* __restrict__ Wihb,
    const ushort* __restrict__ Whhb, const float* __restrict__ bih,
    const float* __restrict__ bhh, const float* __restrict__ G,
    uint* __restrict__ hp0, uint* __restrict__ hp1,
    float* __restrict__ out)
{
    __shared__ __align__(16) ushort Whh_s[96 * 520];   // 99840 B, persistent
    __shared__ __align__(16) char  smem_u[55296];      // As[2] (27648 B each) ∪ gates
    ushort* AsU = (ushort*)smem_u;                     // As[buf]: buf*13824 ushorts
    float*  gs  = (float*)smem_u;                      // gates: g*2304 + row*36 + col

    const int bx = blockIdx.x;
    const int jt = bx >> 4;
    const int bt = ((bx & 7) << 1) | ((bx >> 3) & 1);
    const int jb = jt * 32;
    const int bb = bt * 64;
    const int t  = threadIdx.x;
    const int lane = t & 63;
    const int wv   = t >> 6;
    const int quad = lane >> 4;
    const int l15  = lane & 15;
    const int mh   = wv >> 1;          // wave's 32-row half
    const int cset = wv & 1;           // wave's col-tile triple {cset*3 .. +2}
    const int crow = t >> 2;
    const int cc0  = (t & 3) * 16;
    const int hrow = t >> 2;
    const int hseg = t & 3;

    // --- barrier base: own slot, single-writer => exact, race-free ---
    const unsigned vbase = __hip_atomic_load(&g_prog[(bt << 4) + jt],
                                             __ATOMIC_RELAXED, __HIP_MEMORY_SCOPE_AGENT);

    // --- one-time: Whh slice (3 gates x 32 j-cols, full K) into LDS ---
#pragma unroll
    for (int i = 0; i < 24; ++i) {
        const int gid = i * 256 + t;          // 0..6143
        const int row = gid >> 6;             // 0..95
        const int grp = gid & 63;
        const int grow = (row >> 5) * H_ + jb + (row & 31);
        *(uint4*)&Whh_s[row * 520 + grp * 8] =
            *(const uint4*)(Whhb + (size_t)grow * H_ + grp * 8);
    }

    // --- hoisted biases ---
    float br_[2], bz_[2], bxn_[2], bhn_[2];
#pragma unroll
    for (int nt = 0; nt < 2; ++nt) {
        const int j = jb + nt * 16 + l15;
        br_[nt]  = bih[j] + bhh[j];
        bz_[nt]  = bih[H_ + j] + bhh[H_ + j];
        bxn_[nt] = bih[2 * H_ + j];
        bhn_[nt] = bhh[2 * H_ + j];
    }

    const int hold_kc  = (jb >> 6) << 6;
    const int hold_off = jb & 63;

    const uint* hr = hp0;   // read buffer (packed h)
    uint*       hw = hp1;   // write buffer

    float cr[16];
    unsigned long long hreg[8];
    bf16x8 bi[3][2];        // Wih B-frags for this kc (wave's 3 col-tiles x 2 ks)

    auto load_c = [&](int tstep, int kc) {
        const float4* src = (const float4*)(C + ((size_t)(bb + crow) * S_ + tstep) * H_ + kc + cc0);
        *(float4*)&cr[0]  = src[0];
        *(float4*)&cr[4]  = src[1];
        *(float4*)&cr[8]  = src[2];
        *(float4*)&cr[12] = src[3];
    };
    auto load_h = [&](int kc) {
        const unsigned long long* src = (const unsigned long long*)
            (hr + (size_t)(bb + hrow) * H_ + kc + hseg * 16);
#pragma unroll
        for (int i = 0; i < 8; ++i)
            hreg[i] = __hip_atomic_load(src + i, __ATOMIC_RELAXED, __HIP_MEMORY_SCOPE_AGENT);
    };
    auto loadBi = [&](int kc) {
#pragma unroll
        for (int ct = 0; ct < 3; ++ct) {
            const int ctg = cset * 3 + ct;
            const size_t wrow = (size_t)((ctg >> 1) * H_ + jb + (ctg & 1) * 16 + l15) * H_;
#pragma unroll
            for (int ks2 = 0; ks2 < 2; ++ks2)
                bi[ct][ks2] = *(const bf16x8*)(Wihb + wrow + kc + ks2 * 32 + quad * 8);
        }
    };
    auto write_As = [&](int buf) {
        ushort* base = AsU + buf * 13824;
        __align__(16) ushort cb[16];
#pragma unroll
        for (int u = 0; u < 16; ++u) cb[u] = f2bf(cr[u]);
        uint4* d = (uint4*)&base[crow * 72 + cc0];
        d[0] = ((uint4*)cb)[0]; d[1] = ((uint4*)cb)[1];
        uint hiu[8], lou[8];
#pragma unroll
        for (int i = 0; i < 8; ++i) {
            const uint p0 = (uint)(hreg[i] & 0xFFFFFFFFull);
            const uint p1 = (uint)(hreg[i] >> 32);
            hiu[i] = (p0 >> 16) | (p1 & 0xFFFF0000u);
            lou[i] = (p0 & 0xFFFFu) | (p1 << 16);
        }
        uint4* dh = (uint4*)&base[4608 + hrow * 72 + hseg * 16];
        dh[0] = *(uint4*)&hiu[0]; dh[1] = *(uint4*)&hiu[4];
        uint4* dl = (uint4*)&base[9216 + hrow * 72 + hseg * 16];
        dl[0] = *(uint4*)&lou[0]; dl[1] = *(uint4*)&lou[4];
    };

    // --- prologue ---
    load_c(0, 0); loadBi(0); load_h(0);
    write_As(0);
    __syncthreads();

    for (int tstep = 0; tstep < S_; ++tstep) {
        float g_[4];
#pragma unroll
        for (int r4 = 0; r4 < 4; ++r4)
            g_[r4] = G[(size_t)(bb + wv * 16 + quad * 4 + r4) * S_ + tstep];

        floatx4 accA[2][3], accB[2][2];
#pragma unroll
        for (int rf = 0; rf < 2; ++rf) {
#pragma unroll
            for (int i = 0; i < 3; ++i) accA[rf][i] = (floatx4){0.f, 0.f, 0.f, 0.f};
#pragma unroll
            for (int i = 0; i < 2; ++i) accB[rf][i] = (floatx4){0.f, 0.f, 0.f, 0.f};
        }
        float hold_[2][4];

        for (int kc = 0; kc < H_; kc += 64) {
            const int cur = (kc >> 6) & 1;
            const int kn  = kc + 64;
            if (kn < H_) { load_c(tstep, kn); load_h(kn); }   // consumed in write_As below
            const ushort* Ac = AsU + cur * 13824;
            const ushort* Ah = Ac + 4608;
            const ushort* Al = Ac + 9216;
#pragma unroll
            for (int ks2 = 0; ks2 < 2; ++ks2) {
                const int ao = ks2 * 32 + quad * 8;
                bf16x8 a_c[2], a_hh[2], a_hl[2];
#pragma unroll
                for (int rf = 0; rf < 2; ++rf) {
                    const int ai = (mh * 32 + rf * 16 + l15) * 72 + ao;
                    a_c[rf]  = *(const bf16x8*)&Ac[ai];
                    a_hh[rf] = *(const bf16x8*)&Ah[ai];
                    a_hl[rf] = *(const bf16x8*)&Al[ai];
                }
#pragma unroll
                for (int ct = 0; ct < 3; ++ct) {
                    const int ctg = cset * 3 + ct;
                    const bf16x8 bh = *(const bf16x8*)
                        &Whh_s[((ctg >> 1) * 32 + (ctg & 1) * 16 + l15) * 520 + kc + ao];
#pragma unroll
                    for (int rf = 0; rf < 2; ++rf) {
                        if (ct >= 1 && cset == 1) {   // ctg 4,5: n-gate (xn + hn split)
                            accA[rf][ct]     = __builtin_amdgcn_mfma_f32_16x16x32_bf16(a_c[rf],  bi[ct][ks2], accA[rf][ct],     0, 0, 0);
                            accB[rf][ct - 1] = __builtin_amdgcn_mfma_f32_16x16x32_bf16(a_hh[rf], bh,          accB[rf][ct - 1], 0, 0, 0);
                            accB[rf][ct - 1] = __builtin_amdgcn_mfma_f32_16x16x32_bf16(a_hl[rf], bh,          accB[rf][ct - 1], 0, 0, 0);
                        } else {                      // r / z tiles: single accumulator
                            accA[rf][ct] = __builtin_amdgcn_mfma_f32_16x16x32_bf16(a_c[rf],  bi[ct][ks2], accA[rf][ct], 0, 0, 0);
                            accA[rf][ct] = __builtin_amdgcn_mfma_f32_16x16x32_bf16(a_hh[rf], bh,          accA[rf][ct], 0, 0, 0);
                            accA[rf][ct] = __builtin_amdgcn_mfma_f32_16x16x32_bf16(a_hl[rf], bh,          accA[rf][ct], 0, 0, 0);
                        }
                    }
                }
            }
            if (kn < H_) { loadBi(kn); write_As(cur ^ 1); }   // stage next chunk (dbuf)
            if (kc == hold_kc) {                              // capture h_old from staged tile
#pragma unroll
                for (int nt = 0; nt < 2; ++nt)
#pragma unroll
                    for (int r4 = 0; r4 < 4; ++r4) {
                        const int ai = (wv * 16 + quad * 4 + r4) * 72 + hold_off + nt * 16 + l15;
                        hold_[nt][r4] = bf2f(Ah[ai]) + bf2f(Al[ai]);
                    }
            }
            __syncthreads();
        }

        // --- epilogue: dump gate partials to LDS (aliases dead As buffers) ---
#pragma unroll
        for (int rf = 0; rf < 2; ++rf)
#pragma unroll
        for (int ct = 0; ct < 3; ++ct) {
            const int ctg = cset * 3 + ct;
            const int go  = ctg >> 1;                  // 0:r 1:z 2:xn
            const int col = (ctg & 1) * 16 + l15;
            const int rbase = mh * 32 + rf * 16 + quad * 4;
#pragma unroll
            for (int r = 0; r < 4; ++r)
                gs[go * 2304 + (rbase + r) * 36 + col] = accA[rf][ct][r];
            if (ct >= 1 && cset == 1) {                // hn plane
#pragma unroll
                for (int r = 0; r < 4; ++r)
                    gs[3 * 2304 + (rbase + r) * 36 + col] = accB[rf][ct - 1][r];
            }
        }
        __syncthreads();

        // --- read back gates, compute h_new, write-through packed ---
        const int last = (tstep == S_ - 1);
#pragma unroll
        for (int nt = 0; nt < 2; ++nt) {
            const int j = jb + nt * 16 + l15;
#pragma unroll
            for (int r4 = 0; r4 < 4; ++r4) {
                const int row = wv * 16 + quad * 4 + r4;
                const int b = bb + row;
                const size_t idx = (size_t)b * H_ + j;
                const int gidx = row * 36 + nt * 16 + l15;
                const float rrv = gs[0 * 2304 + gidx];
                const float zzv = gs[1 * 2304 + gidx];
                const float xnv = gs[2 * 2304 + gidx];
                const float hnv = gs[3 * 2304 + gidx];
                const float hold = hold_[nt][r4];
                const float g = g_[r4];
                const float rg = 1.f / (1.f + expf(-(rrv + br_[nt])));
                const float zg = 1.f / (1.f + expf(-(zzv + bz_[nt])));
                const float ng = tanhf(xnv + bxn_[nt] + rg * (hnv + bhn_[nt]));
                const float hgru = (1.f - zg) * ng + zg * hold;
                const float hnew = g * hgru + (1.f - g) * hold;
                const ushort hb = f2bf(hnew);
                const ushort hl = f2bf(hnew - bf2f(hb));
                __hip_atomic_store(&hw[idx], ((uint)hb << 16) | (uint)hl,
                                   __ATOMIC_RELAXED, __HIP_MEMORY_SCOPE_AGENT);
                if (last) out[idx] = hnew;
            }
        }
        if (last) break;

        // swap read/write buffers
        { uint* tmp = hw; hw = (uint*)hr; hr = (const uint*)tmp; }

        // prefetch next step's C / Wih-frags before the barrier (h-independent)
        load_c(tstep + 1, 0);
        loadBi(0);

        // --- per-b-tile barrier: 16 blocks, no fences (R7, proven) ---
        asm volatile("s_waitcnt vmcnt(0)" ::: "memory");   // all waves drain h stores
        __syncthreads();                                   // ... before t0 flags
        if (t == 0)
            __hip_atomic_store(&g_prog[(bt << 4) + jt], vbase + (unsigned)(tstep + 1),
                               __ATOMIC_RELAXED, __HIP_MEMORY_SCOPE_AGENT);
        if (wv == 0) {
            const unsigned tgt = vbase + (unsigned)(tstep + 1);
            const int slot = (bt << 4) + (t & 15);
            while (true) {
                const unsigned v = __hip_atomic_load(&g_prog[slot],
                                                     __ATOMIC_RELAXED, __HIP_MEMORY_SCOPE_AGENT);
                if (__all(v >= tgt)) break;
                __builtin_amdgcn_s_sleep(2);
            }
        }
        __syncthreads();

        load_h(0);          // h(t+1) readable only after the barrier
        write_As(0);        // stage kc=0 for next step
        __syncthreads();
    }
}

extern "C" void kernel_launch(void* const* d_in, const int* in_sizes, int n_in,
                              void* d_out, int out_size, void* d_ws, size_t ws_size,
                              hipStream_t stream) {
    (void)in_sizes; (void)n_in; (void)out_size; (void)ws_size;
    const float* C    = (const float*)d_in[0];
    const float* Q    = (const float*)d_in[1];
    const float* M    = (const float*)d_in[2];
    const float* fc1w = (const float*)d_in[3];
    const float* fc1b = (const float*)d_in[4];
    const float* fc2w = (const float*)d_in[5];
    const float* fc2b = (const float*)d_in[6];
    const float* Wih  = (const float*)d_in[7];
    const float* Whh  = (const float*)d_in[8];
    const float* bih  = (const float*)d_in[9];
    const float* bhh  = (const float*)d_in[10];
    float* out = (float*)d_out;

    char* ws = (char*)d_ws;
    float* Gbuf  = (float*)ws;                           // 256 KB
    uint*  hp0   = (uint*)(ws + 262144);                 // 2 MB (packed h, buf 0)
    uint*  hp1   = (uint*)(ws + 262144 + 2097152);       // 2 MB (packed h, buf 1)
    ushort* fc1wb = (ushort*)(ws + 4456448);             // 480 KB
    ushort* Wihb  = (ushort*)(ws + 4947968);             // 1.5 MB
    ushort* Whhb  = (ushort*)(ws + 6520832);             // 1.5 MB (ends ~7.72 MB)

    // h0 = 0: zero packed buffer 0 (buffer 1 fully written at t=0)
    hipMemsetAsync(hp0, 0, 2097152, stream);

    prep_w<<<256, 256, 0, stream>>>(fc1w, fc1wb, Wih, Wihb, Whh, Whhb);
    g_kernel<<<B_, 256, 0, stream>>>(C, Q, M, fc1wb, fc1b, fc2w, fc2b, Gbuf);
    scan_all<<<256, 256, 0, stream>>>(C, Wihb, Whhb, bih, bhh, Gbuf,
                                      hp0, hp1, out);
}